// Round 1
// baseline (190.444 us; speedup 1.0000x reference)
//
#include <hip/hip_runtime.h>
#include <cstdint>

#define NB 4
#define ND 1024
#define NT 2048
#define NH 16
#define NE 64

typedef __bf16 bf16x8 __attribute__((ext_vector_type(8)));
typedef float f32x4 __attribute__((ext_vector_type(4)));
typedef unsigned short us8 __attribute__((ext_vector_type(8)));

__device__ __forceinline__ unsigned short f2bf(float f) {
  unsigned u = __builtin_bit_cast(unsigned, f);
  return (unsigned short)((u + 0x7fffu + ((u >> 16) & 1u)) >> 16);  // RTNE
}

// async global->LDS, 16B per lane; LDS dest must be wave-uniform base + lane*16
__device__ __forceinline__ void gload16(const void* g, void* l) {
  __builtin_amdgcn_global_load_lds(
      (const __attribute__((address_space(1))) void*)(uintptr_t)g,
      (__attribute__((address_space(3))) void*)(uintptr_t)l, 16, 0, 0);
}

// ---------------------------------------------------------------- prep ------
// Cast Wp, Wo to bf16; build Gf[h][i] = bf16round(tw[h][i-(T-1)]) widened to
// f32 (zero outside [0,T)), so Toeplitz fragments are top-16-bit extracts.
__global__ void prep_kernel(const float* __restrict__ Wp, const float* __restrict__ Wo,
                            const float* __restrict__ tw,
                            unsigned short* __restrict__ WpB, unsigned short* __restrict__ WoB,
                            float* __restrict__ Gf) {
  int idx = blockIdx.x * 256 + threadIdx.x;
  int stride = gridDim.x * 256;
  for (int i = idx; i < ND * ND; i += stride) WpB[i] = f2bf(Wp[i]);
  for (int i = idx; i < ND * ND; i += stride) WoB[i] = f2bf(Wo[i]);
  for (int i = idx; i < NH * 2 * NT; i += stride) {
    int h = i >> 12, k = i & 4095;
    int d = k - (NT - 1);
    float v = 0.f;
    if (d >= 0 && d < NT) {
      unsigned short b = f2bf(tw[h * NT + d]);
      v = __builtin_bit_cast(float, (unsigned)b << 16);
    }
    Gf[i] = v;
  }
}

// ------------------------------------------------------- transpose + cast ---
// x (B,D,T) f32 -> xT (B,T,D) bf16. 32x32 LDS tile.
__global__ __launch_bounds__(256) void transpose_cast(const float* __restrict__ x,
                                                      unsigned short* __restrict__ xT) {
  __shared__ float tile[32][33];
  int tx = threadIdx.x & 31, ty = threadIdx.x >> 5;  // ty in 0..7
  int t0 = blockIdx.x * 32, d0 = blockIdx.y * 32, b = blockIdx.z;
  const float* xb = x + (long)b * ND * NT;
#pragma unroll
  for (int k = 0; k < 4; ++k)
    tile[ty + 8 * k][tx] = xb[(long)(d0 + ty + 8 * k) * NT + t0 + tx];
  __syncthreads();
  unsigned short* xTb = xT + (long)b * NT * ND;
#pragma unroll
  for (int k = 0; k < 4; ++k)
    xTb[(long)(t0 + ty + 8 * k) * ND + d0 + tx] = f2bf(tile[tx][ty + 8 * k]);
}

// ----------------------------------------------------------- gemm_bt --------
// C[b][m][n] = sum_k A[m][k] * Bt[b][n][k] + bias[m]
// M=1024, N=2048, K=1024. 128x128 tile, BK=32, 4 waves of 64x64, 16x16x32 MFMA.
template <bool OUT_BF16>
__global__ __launch_bounds__(256, 2) void gemm_bt(const unsigned short* __restrict__ A,
                                                  const unsigned short* __restrict__ Bt,
                                                  const float* __restrict__ bias,
                                                  void* __restrict__ Cb, long strideB,
                                                  long strideC) {
  const int M = 1024, N = 2048, K = 1024;
  (void)M;
  __shared__ __align__(16) unsigned short As[128 * 32];
  __shared__ __align__(16) unsigned short Bs[128 * 32];
  const int tid = threadIdx.x;
  const int lane = tid & 63;
  const int wid = tid >> 6;
  const int wm = (wid & 1) * 64, wn = (wid >> 1) * 64;
  const int m0 = blockIdx.y * 128, n0 = blockIdx.x * 128;
  const unsigned short* Bb = Bt + (long)blockIdx.z * strideB;
  const int mlo = lane & 15, q = lane >> 4;

  f32x4 acc[4][4] = {};
  for (int k0 = 0; k0 < K; k0 += 32) {
#pragma unroll
    for (int p = 0; p < 2; ++p) {
      int idx = p * 256 + tid;
      int row = idx >> 2, kc = (idx & 3) * 8;
      gload16(A + (long)(m0 + row) * K + k0 + kc, &As[idx * 8]);
      gload16(Bb + (long)(n0 + row) * K + k0 + kc, &Bs[idx * 8]);
    }
    __syncthreads();
    bf16x8 av[4], bv[4];
#pragma unroll
    for (int i = 0; i < 4; ++i) {
      av[i] = __builtin_bit_cast(bf16x8, *(const us8*)&As[(wm + i * 16 + mlo) * 32 + q * 8]);
      bv[i] = __builtin_bit_cast(bf16x8, *(const us8*)&Bs[(wn + i * 16 + mlo) * 32 + q * 8]);
    }
#pragma unroll
    for (int i = 0; i < 4; ++i)
#pragma unroll
      for (int j = 0; j < 4; ++j)
        acc[i][j] = __builtin_amdgcn_mfma_f32_16x16x32_bf16(av[i], bv[j], acc[i][j], 0, 0, 0);
    __syncthreads();
  }
  // epilogue: C/D layout col=lane&15, row=(lane>>4)*4+r
#pragma unroll
  for (int i = 0; i < 4; ++i)
#pragma unroll
    for (int j = 0; j < 4; ++j)
#pragma unroll
      for (int r = 0; r < 4; ++r) {
        int gr = m0 + wm + i * 16 + q * 4 + r;
        int gc = n0 + wn + j * 16 + mlo;
        float v = acc[i][j][r] + bias[gr];
        if (OUT_BF16)
          ((unsigned short*)Cb)[(long)blockIdx.z * strideC + (long)gr * N + gc] = f2bf(v);
        else
          ((float*)Cb)[(long)blockIdx.z * strideC + (long)gr * N + gc] = v;
      }
}

// ----------------------------------------------------------- toeplitz -------
// mixedT[b][t][h*64+e] = sum_{s<=t} tw[h][t-s] * proj[b][h*64+e][s]
// Block: one (t-tile of 128, h, pair of b). 4 waves, each 32(t) x 128(n),
// n = bb*64 + e over 2 batches. BK=32. A (Toeplitz) built from LDS Gs gathers.
__global__ __launch_bounds__(256, 2) void toeplitz(const unsigned short* __restrict__ proj,
                                                   const float* __restrict__ Gf,
                                                   unsigned short* __restrict__ mixedT) {
  __shared__ float Gs[2176];
  __shared__ __align__(16) unsigned short Bs[128 * 32];
  const int tid = threadIdx.x, lane = tid & 63, w = tid >> 6;
  const int t0 = blockIdx.x * 128, h = blockIdx.y, zb = blockIdx.z;  // zb 0..1
  const int mlo = lane & 15, q = lane >> 4;

  // Gs[i] = G[h][T-128+i]  => value tw[h][d] at Gs[d+127] (0 for d<0)
  const float* Gh = Gf + h * 2 * NT;
  const int glen = t0 + 256;  // covers d in [-127, t0+128]
  for (int i = tid; i < glen; i += 256) Gs[i] = Gh[NT - 128 + i];

  f32x4 acc[2][8] = {};
  const int kend = t0 + 128;
  for (int s0 = 0; s0 < kend; s0 += 32) {
#pragma unroll
    for (int p = 0; p < 2; ++p) {
      int idx = p * 256 + tid;
      int n = idx >> 2, kc = (idx & 3) * 8;  // n in 0..127
      int bb = n >> 6, e = n & 63;
      gload16(proj + ((long)(zb * 2 + bb) * ND + h * 64 + e) * NT + s0 + kc, &Bs[idx * 8]);
    }
    __syncthreads();
    bf16x8 av[2];
#pragma unroll
    for (int i = 0; i < 2; ++i) {
      // A[m][k] = tw[h][t-s]; Gs index = (t-s)+127, descending in j
      int base = (t0 + w * 32 + i * 16 + mlo) - (s0 + q * 8) + 127;
      us8 au;
#pragma unroll
      for (int j = 0; j < 8; ++j)
        au[j] = (unsigned short)(__builtin_bit_cast(unsigned, Gs[base - j]) >> 16);
      av[i] = __builtin_bit_cast(bf16x8, au);
    }
    bf16x8 bv[8];
#pragma unroll
    for (int j = 0; j < 8; ++j)
      bv[j] = __builtin_bit_cast(bf16x8, *(const us8*)&Bs[(j * 16 + mlo) * 32 + q * 8]);
#pragma unroll
    for (int i = 0; i < 2; ++i)
#pragma unroll
      for (int j = 0; j < 8; ++j)
        acc[i][j] = __builtin_amdgcn_mfma_f32_16x16x32_bf16(av[i], bv[j], acc[i][j], 0, 0, 0);
    __syncthreads();
  }
#pragma unroll
  for (int i = 0; i < 2; ++i)
#pragma unroll
    for (int j = 0; j < 8; ++j)
#pragma unroll
      for (int r = 0; r < 4; ++r) {
        int t = t0 + w * 32 + i * 16 + q * 4 + r;
        int n = j * 16 + mlo;
        int bb = n >> 6, e = n & 63;
        mixedT[((long)(zb * 2 + bb) * NT + t) * ND + h * 64 + e] = f2bf(acc[i][j][r]);
      }
}

// ---------------------------------------------------------------------------
extern "C" void kernel_launch(void* const* d_in, const int* in_sizes, int n_in, void* d_out,
                              int out_size, void* d_ws, size_t ws_size, hipStream_t stream) {
  const float* x = (const float*)d_in[0];
  const float* Wp = (const float*)d_in[1];
  const float* bp = (const float*)d_in[2];
  const float* tw = (const float*)d_in[3];
  const float* Wo = (const float*)d_in[4];
  const float* bo = (const float*)d_in[5];
  float* out = (float*)d_out;

  char* ws = (char*)d_ws;
  // layout (bytes): [0,16M) xT / mixedT (reused)  [16M,32M) proj
  //                 [32M,34M) WpB  [34M,36M) WoB  [36M,+256K) Gf
  unsigned short* xT = (unsigned short*)(ws);  // also mixedT after stage 2
  unsigned short* proj = (unsigned short*)(ws + (16ull << 20));
  unsigned short* WpB = (unsigned short*)(ws + (32ull << 20));
  unsigned short* WoB = (unsigned short*)(ws + (34ull << 20));
  float* Gf = (float*)(ws + (36ull << 20));

  prep_kernel<<<dim3(2048), 256, 0, stream>>>(Wp, Wo, tw, WpB, WoB, Gf);
  transpose_cast<<<dim3(NT / 32, ND / 32, NB), 256, 0, stream>>>(x, xT);
  // stage 1: proj[b][he][t] = Wp @ x[b] + bp
  gemm_bt<true><<<dim3(16, 8, NB), 256, 0, stream>>>(WpB, xT, bp, proj, (long)NT * ND,
                                                     (long)ND * NT);
  // stage 2: mixedT[b][t][he] (written into xT buffer)
  toeplitz<<<dim3(NT / 128, NH, NB / 2), 256, 0, stream>>>(proj, Gf, xT);
  // stage 3: out[b][d][t] = Wo @ mixedT[b]^T + bo
  gemm_bt<false><<<dim3(16, 8, NB), 256, 0, stream>>>(WoB, xT, bo, out, (long)NT * ND,
                                                      (long)ND * NT);
}